// Round 1
// baseline (770.733 us; speedup 1.0000x reference)
//
#include <hip/hip_runtime.h>
#include <cstdio>

typedef __attribute__((ext_vector_type(8))) short short8;
typedef __attribute__((ext_vector_type(4))) float f32x4;

// ---------- helpers ----------

__device__ __forceinline__ unsigned short bf16r(float f) {
  union { float f; unsigned int u; } x; x.f = f;
  unsigned int r = x.u + 0x7fffu + ((x.u >> 16) & 1u);
  return (unsigned short)(r >> 16);
}

__device__ __forceinline__ void gload_lds16(const void* g, void* l) {
  __builtin_amdgcn_global_load_lds((const __attribute__((address_space(1))) void*)g,
                                   (__attribute__((address_space(3))) void*)l,
                                   16, 0, 0);
}

// ---------- conversion kernels ----------

// fp32 -> bf16 bits, vectorized 4 at a time (n4 = n/4)
__global__ void cvt_f32_bf16(const float* __restrict__ in, unsigned short* __restrict__ out, int n4) {
  int i = blockIdx.x * blockDim.x + threadIdx.x;
  int stride = gridDim.x * blockDim.x;
  for (; i < n4; i += stride) {
    float4 v = reinterpret_cast<const float4*>(in)[i];
    ushort4 o;
    o.x = bf16r(v.x); o.y = bf16r(v.y); o.z = bf16r(v.z); o.w = bf16r(v.w);
    reinterpret_cast<ushort4*>(out)[i] = o;
  }
}

// k_cache [100][4096] fp32 -> kpad [128][4096] bf16, rows >=100 zero
__global__ void build_kpad(const float* __restrict__ kc, unsigned short* __restrict__ kpad) {
  int idx = blockIdx.x * blockDim.x + threadIdx.x;   // over 128*4096
  if (idx >= 128 * 4096) return;
  int row = idx >> 12;
  float v = 0.f;
  if (row < 100) v = kc[idx];
  kpad[idx] = bf16r(v);
}

// v_cache [100][4096] fp32 -> vt [4096][128] bf16 (vt[h][l] = v[l][h], l>=100 zero)
__global__ void build_vt(const float* __restrict__ vc, unsigned short* __restrict__ vt) {
  int idx = blockIdx.x * blockDim.x + threadIdx.x;   // over 128*4096, idx = l*4096 + h
  if (idx >= 128 * 4096) return;
  int l = idx >> 12;
  int h = idx & 4095;
  float v = 0.f;
  if (l < 100) v = vc[idx];
  vt[(size_t)h * 128 + l] = bf16r(v);
}

// ---------- softmax over 101 valid cols of S[8192][128] -> W bf16 [8192][128] ----------

__global__ void softmax_rows(const float* __restrict__ S, unsigned short* __restrict__ W, int rows) {
  int wave = threadIdx.x >> 6;
  int lane = threadIdx.x & 63;
  int row = blockIdx.x * (blockDim.x >> 6) + wave;
  if (row >= rows) return;
  const float scale = 0.088388347648318447f;   // 1/sqrt(128)
  float2 v = reinterpret_cast<const float2*>(S + (size_t)row * 128)[lane];
  int c0 = lane * 2, c1 = c0 + 1;
  float s0 = (c0 <= 100) ? v.x * scale : -1e30f;
  float s1 = (c1 <= 100) ? v.y * scale : -1e30f;
  float m = fmaxf(s0, s1);
  #pragma unroll
  for (int off = 1; off < 64; off <<= 1) m = fmaxf(m, __shfl_xor(m, off));
  float e0 = (c0 <= 100) ? __expf(s0 - m) : 0.f;
  float e1 = (c1 <= 100) ? __expf(s1 - m) : 0.f;
  float sum = e0 + e1;
  #pragma unroll
  for (int off = 1; off < 64; off <<= 1) sum += __shfl_xor(sum, off);
  float inv = 1.f / sum;
  ushort2 o;
  o.x = bf16r(e0 * inv);
  o.y = bf16r(e1 * inv);
  reinterpret_cast<ushort2*>(W + (size_t)row * 128)[lane] = o;
}

// ---------- NT GEMM: C[M,N] = A[M,K] * B[N,K]^T (+bias), bf16 in, fp32 acc ----------
// m97 structure: 128x128 tile, BK=32, 4 waves (2x2), 4x4 16x16x32 MFMA frags/wave,
// global_load_lds width=16 staging, single LDS buffer, 2 barriers per K-step.

template<bool ADD_BIAS, bool OUT_F32>
__global__ void gemm_nt(const unsigned short* __restrict__ A,
                        const unsigned short* __restrict__ B,
                        const float* __restrict__ bias,
                        void* __restrict__ Cout,
                        int M, int N, int K) {
  __shared__ unsigned short As[128][32];   // 8 KB
  __shared__ unsigned short Bs[128][32];   // 8 KB

  const int tid  = threadIdx.x;
  const int wave = tid >> 6;
  const int lane = tid & 63;
  const int wm = wave >> 1;          // 0..1
  const int wn = wave & 1;           // 0..1
  const size_t rowA0 = (size_t)blockIdx.y * 128;
  const size_t colB0 = (size_t)blockIdx.x * 128;

  f32x4 acc[4][4] = {};

  // staging: each thread brings one 16B chunk per issue; wave-uniform LDS dest
  const int sr = wave * 16 + (lane >> 2);     // row within 64-row half
  const int sc = (lane & 3) << 3;             // element col (0,8,16,24)

  const unsigned short* Ap0 = A + (rowA0 + sr) * K + sc;
  const unsigned short* Ap1 = A + (rowA0 + 64 + sr) * K + sc;
  const unsigned short* Bp0 = B + (colB0 + sr) * K + sc;
  const unsigned short* Bp1 = B + (colB0 + 64 + sr) * K + sc;
  unsigned short* AsD0 = &As[wave * 16][0];
  unsigned short* AsD1 = &As[64 + wave * 16][0];
  unsigned short* BsD0 = &Bs[wave * 16][0];
  unsigned short* BsD1 = &Bs[64 + wave * 16][0];

  const int fr = lane & 15;            // fragment row
  const int fk = (lane >> 4) << 3;     // fragment k offset (0,8,16,24)

  for (int k0 = 0; k0 < K; k0 += 32) {
    gload_lds16(Ap0 + k0, AsD0);
    gload_lds16(Ap1 + k0, AsD1);
    gload_lds16(Bp0 + k0, BsD0);
    gload_lds16(Bp1 + k0, BsD1);
    __syncthreads();   // compiler drains vmcnt -> LDS tiles ready

    short8 av[4], bv[4];
    #pragma unroll
    for (int mi = 0; mi < 4; ++mi)
      av[mi] = *reinterpret_cast<const short8*>(&As[wm * 64 + mi * 16 + fr][fk]);
    #pragma unroll
    for (int ni = 0; ni < 4; ++ni)
      bv[ni] = *reinterpret_cast<const short8*>(&Bs[wn * 64 + ni * 16 + fr][fk]);
    #pragma unroll
    for (int mi = 0; mi < 4; ++mi)
      #pragma unroll
      for (int ni = 0; ni < 4; ++ni)
        acc[mi][ni] = __builtin_amdgcn_mfma_f32_16x16x32_bf16(av[mi], bv[ni], acc[mi][ni], 0, 0, 0);
    __syncthreads();   // everyone done reading before next stage
  }

  // epilogue: C/D layout col=lane&15, row=(lane>>4)*4+j  [guide m89/m91]
  const int orow = (lane >> 4) * 4;
  const int ocol = lane & 15;
  #pragma unroll
  for (int mi = 0; mi < 4; ++mi) {
    #pragma unroll
    for (int ni = 0; ni < 4; ++ni) {
      size_t r0 = rowA0 + wm * 64 + mi * 16 + orow;
      size_t c  = colB0 + wn * 64 + ni * 16 + ocol;
      float bv_ = ADD_BIAS ? bias[c] : 0.f;
      #pragma unroll
      for (int j = 0; j < 4; ++j) {
        float v = acc[mi][ni][j] + bv_;
        if (OUT_F32) ((float*)Cout)[(r0 + j) * (size_t)N + c] = v;
        else         ((unsigned short*)Cout)[(r0 + j) * (size_t)N + c] = bf16r(v);
      }
    }
  }
}

// ---------- launch ----------

extern "C" void kernel_launch(void* const* d_in, const int* in_sizes, int n_in,
                              void* d_out, int out_size, void* d_ws, size_t ws_size,
                              hipStream_t stream) {
  const float* x       = (const float*)d_in[0];   // [8192,4096]
  const float* q_w     = (const float*)d_in[1];   // [4096,4096]
  const float* q_b     = (const float*)d_in[2];   // [4096]
  const float* k_cache = (const float*)d_in[3];   // [100,4096]
  const float* v_cache = (const float*)d_in[4];   // [100,4096]
  const float* out_w   = (const float*)d_in[5];   // [4096,4096]
  const float* out_b   = (const float*)d_in[6];   // [4096]
  float* out = (float*)d_out;

  const int M = 8192, H = 4096;

  // workspace layout (bytes); attn reuses the x_bf16 buffer (x dead after GEMM1)
  char* ws = (char*)d_ws;
  size_t off = 0;
  unsigned short* x_bf    = (unsigned short*)(ws + off); off += (size_t)M * H * 2;       // 64 MB
  unsigned short* attn_bf = x_bf;                                                         // reuse
  unsigned short* qw_bf   = (unsigned short*)(ws + off); off += (size_t)H * H * 2;       // 32 MB
  unsigned short* outw_bf = (unsigned short*)(ws + off); off += (size_t)H * H * 2;       // 32 MB
  unsigned short* kpad    = (unsigned short*)(ws + off); off += (size_t)128 * H * 2;     // 1 MB
  unsigned short* vt      = (unsigned short*)(ws + off); off += (size_t)H * 128 * 2;     // 1 MB
  unsigned short* q_bf    = (unsigned short*)(ws + off); off += (size_t)M * H * 2;       // 64 MB
  float*          S       = (float*)(ws + off);          off += (size_t)M * 128 * 4;     // 4 MB
  unsigned short* W       = (unsigned short*)(ws + off); off += (size_t)M * 128 * 2;     // 2 MB
  if (ws_size < off) { fprintf(stderr, "ws too small: need %zu have %zu\n", off, ws_size); return; }

  // 1) precision conversions / layout builds
  cvt_f32_bf16<<<2048, 256, 0, stream>>>(x, x_bf, M * H / 4);
  cvt_f32_bf16<<<1024, 256, 0, stream>>>(q_w, qw_bf, H * H / 4);
  cvt_f32_bf16<<<1024, 256, 0, stream>>>(out_w, outw_bf, H * H / 4);
  build_kpad<<<2048, 256, 0, stream>>>(k_cache, kpad);
  build_vt<<<2048, 256, 0, stream>>>(v_cache, vt);

  // 2) q = x @ q_w^T + q_b  -> bf16
  gemm_nt<true, false><<<dim3(H / 128, M / 128), 256, 0, stream>>>(x_bf, qw_bf, q_b, q_bf, M, H, H);

  // 3) S = q @ kpad^T (fp32; col100 is exactly 0 via zero kpad row)
  gemm_nt<false, true><<<dim3(1, M / 128), 256, 0, stream>>>(q_bf, kpad, nullptr, S, M, 128, H);

  // 4) softmax over cols 0..100, W bf16, cols>100 zeroed
  softmax_rows<<<M / 4, 256, 0, stream>>>(S, W, M);

  // 5) attn = W @ vt^T -> bf16 (vt rows are v columns; l>=100 zero)
  gemm_nt<false, false><<<dim3(H / 128, M / 128), 256, 0, stream>>>(W, vt, nullptr, attn_bf, M, H, 128);

  // 6) out = attn @ out_w^T + out_b -> fp32
  gemm_nt<true, true><<<dim3(H / 128, M / 128), 256, 0, stream>>>(attn_bf, outw_bf, out_b, out, M, H, H);
}

// Round 2
// 692.163 us; speedup vs baseline: 1.1135x; 1.1135x over previous
//
#include <hip/hip_runtime.h>
#include <cstdio>

typedef __attribute__((ext_vector_type(8))) short short8;
typedef __attribute__((ext_vector_type(4))) float f32x4;

// ---------- helpers ----------

__device__ __forceinline__ unsigned short bf16r(float f) {
  union { float f; unsigned int u; } x; x.f = f;
  unsigned int r = x.u + 0x7fffu + ((x.u >> 16) & 1u);
  return (unsigned short)(r >> 16);
}

__device__ __forceinline__ void gload_lds16(const void* g, void* l) {
  __builtin_amdgcn_global_load_lds((const __attribute__((address_space(1))) void*)g,
                                   (__attribute__((address_space(3))) void*)l,
                                   16, 0, 0);
}

// ---------- conversion kernels ----------

__global__ void cvt_f32_bf16(const float* __restrict__ in, unsigned short* __restrict__ out, int n4) {
  int i = blockIdx.x * blockDim.x + threadIdx.x;
  int stride = gridDim.x * blockDim.x;
  for (; i < n4; i += stride) {
    float4 v = reinterpret_cast<const float4*>(in)[i];
    ushort4 o;
    o.x = bf16r(v.x); o.y = bf16r(v.y); o.z = bf16r(v.z); o.w = bf16r(v.w);
    reinterpret_cast<ushort4*>(out)[i] = o;
  }
}

__global__ void build_kpad(const float* __restrict__ kc, unsigned short* __restrict__ kpad) {
  int idx = blockIdx.x * blockDim.x + threadIdx.x;
  if (idx >= 128 * 4096) return;
  int row = idx >> 12;
  float v = 0.f;
  if (row < 100) v = kc[idx];
  kpad[idx] = bf16r(v);
}

__global__ void build_vt(const float* __restrict__ vc, unsigned short* __restrict__ vt) {
  int idx = blockIdx.x * blockDim.x + threadIdx.x;
  if (idx >= 128 * 4096) return;
  int l = idx >> 12;
  int h = idx & 4095;
  float v = 0.f;
  if (l < 100) v = vc[idx];
  vt[(size_t)h * 128 + l] = bf16r(v);
}

// ---------- softmax ----------

__global__ void softmax_rows(const float* __restrict__ S, unsigned short* __restrict__ W, int rows) {
  int wave = threadIdx.x >> 6;
  int lane = threadIdx.x & 63;
  int row = blockIdx.x * (blockDim.x >> 6) + wave;
  if (row >= rows) return;
  const float scale = 0.088388347648318447f;   // 1/sqrt(128)
  float2 v = reinterpret_cast<const float2*>(S + (size_t)row * 128)[lane];
  int c0 = lane * 2, c1 = c0 + 1;
  float s0 = (c0 <= 100) ? v.x * scale : -1e30f;
  float s1 = (c1 <= 100) ? v.y * scale : -1e30f;
  float m = fmaxf(s0, s1);
  #pragma unroll
  for (int off = 1; off < 64; off <<= 1) m = fmaxf(m, __shfl_xor(m, off));
  float e0 = (c0 <= 100) ? __expf(s0 - m) : 0.f;
  float e1 = (c1 <= 100) ? __expf(s1 - m) : 0.f;
  float sum = e0 + e1;
  #pragma unroll
  for (int off = 1; off < 64; off <<= 1) sum += __shfl_xor(sum, off);
  float inv = 1.f / sum;
  ushort2 o;
  o.x = bf16r(e0 * inv);
  o.y = bf16r(e1 * inv);
  reinterpret_cast<ushort2*>(W + (size_t)row * 128)[lane] = o;
}

// ---------- m97-style 128^2 NT GEMM (kept for S-GEMM N=128 and PV-GEMM K=128) ----------

template<bool ADD_BIAS, bool OUT_F32>
__global__ void gemm_nt(const unsigned short* __restrict__ A,
                        const unsigned short* __restrict__ B,
                        const float* __restrict__ bias,
                        void* __restrict__ Cout,
                        int M, int N, int K) {
  __shared__ unsigned short As[128][32];
  __shared__ unsigned short Bs[128][32];

  const int tid  = threadIdx.x;
  const int wave = tid >> 6;
  const int lane = tid & 63;
  const int wm = wave >> 1;
  const int wn = wave & 1;
  const size_t rowA0 = (size_t)blockIdx.y * 128;
  const size_t colB0 = (size_t)blockIdx.x * 128;

  f32x4 acc[4][4] = {};

  const int sr = wave * 16 + (lane >> 2);
  const int sc = (lane & 3) << 3;

  const unsigned short* Ap0 = A + (rowA0 + sr) * K + sc;
  const unsigned short* Ap1 = A + (rowA0 + 64 + sr) * K + sc;
  const unsigned short* Bp0 = B + (colB0 + sr) * K + sc;
  const unsigned short* Bp1 = B + (colB0 + 64 + sr) * K + sc;
  unsigned short* AsD0 = &As[wave * 16][0];
  unsigned short* AsD1 = &As[64 + wave * 16][0];
  unsigned short* BsD0 = &Bs[wave * 16][0];
  unsigned short* BsD1 = &Bs[64 + wave * 16][0];

  const int fr = lane & 15;
  const int fk = (lane >> 4) << 3;

  for (int k0 = 0; k0 < K; k0 += 32) {
    gload_lds16(Ap0 + k0, AsD0);
    gload_lds16(Ap1 + k0, AsD1);
    gload_lds16(Bp0 + k0, BsD0);
    gload_lds16(Bp1 + k0, BsD1);
    __syncthreads();

    short8 av[4], bv[4];
    #pragma unroll
    for (int mi = 0; mi < 4; ++mi)
      av[mi] = *reinterpret_cast<const short8*>(&As[wm * 64 + mi * 16 + fr][fk]);
    #pragma unroll
    for (int ni = 0; ni < 4; ++ni)
      bv[ni] = *reinterpret_cast<const short8*>(&Bs[wn * 64 + ni * 16 + fr][fk]);
    #pragma unroll
    for (int mi = 0; mi < 4; ++mi)
      #pragma unroll
      for (int ni = 0; ni < 4; ++ni)
        acc[mi][ni] = __builtin_amdgcn_mfma_f32_16x16x32_bf16(av[mi], bv[ni], acc[mi][ni], 0, 0, 0);
    __syncthreads();
  }

  const int orow = (lane >> 4) * 4;
  const int ocol = lane & 15;
  #pragma unroll
  for (int mi = 0; mi < 4; ++mi) {
    #pragma unroll
    for (int ni = 0; ni < 4; ++ni) {
      size_t r0 = rowA0 + wm * 64 + mi * 16 + orow;
      size_t c  = colB0 + wn * 64 + ni * 16 + ocol;
      float bv_ = ADD_BIAS ? bias[c] : 0.f;
      #pragma unroll
      for (int j = 0; j < 4; ++j) {
        float v = acc[mi][ni][j] + bv_;
        if (OUT_F32) ((float*)Cout)[(r0 + j) * (size_t)N + c] = v;
        else         ((unsigned short*)Cout)[(r0 + j) * (size_t)N + c] = bf16r(v);
      }
    }
  }
}

// ---------- 256^2 8-phase NT GEMM (T1+T2+T3+T4+T5) ----------
// BM=BN=256, BK=64 (tile pair of 2 K-tiles per iteration), 8 waves (2M x 4N),
// per-wave output 128x64, acc[8][4] f32x4. LDS 128 KiB: A/B x 2 buf x 2 half x [128][64].
// Swizzle: 16B slot s at row r stored at slot s^(r&7); inverse-permuted global source,
// linear global_load_lds dest, XOR on ds_read addresses.
// Stage schedule (iteration computes tiles T=2i buf0, T+1 buf1):
//   ph1: A(T+1).h0  ph2: A(T+1).h1  ph3: B(T+2).h0  ph4: B(T+2).h1 + vmcnt(4)
//   ph5: A(T+2).h0  ph6: A(T+2).h1  ph7: B(T+3).h0  ph8: B(T+3).h1 + vmcnt(4)
// B-frags (8 x short8) loaded at ph1/ph5 and held, so B LDS regions are free after
// phase 1/5 — this is what makes 8 stages/iteration legal with 2 buffers.
// Last iteration peeled: only A(T+1) staged, vmcnt(0) at ph4.

template<int MH>
__device__ __forceinline__ void load_a(short8 (&af)[4][2], const unsigned short* base,
                                       int c0, int c1) {
  #pragma unroll
  for (int im = 0; im < 4; ++im) {
    af[im][0] = *reinterpret_cast<const short8*>(base + MH * 4096 + im * 1024 + c0);
    af[im][1] = *reinterpret_cast<const short8*>(base + MH * 4096 + im * 1024 + c1);
  }
}

__device__ __forceinline__ void load_b(short8 (&bf)[4][2], const unsigned short* base,
                                       int c0, int c1) {
  #pragma unroll
  for (int ni = 0; ni < 4; ++ni) {
    bf[ni][0] = *reinterpret_cast<const short8*>(base + ni * 1024 + c0);
    bf[ni][1] = *reinterpret_cast<const short8*>(base + ni * 1024 + c1);
  }
}

template<int MH, int NH>
__device__ __forceinline__ void mma16(const short8 (&af)[4][2], const short8 (&bf)[4][2],
                                      f32x4 (&acc)[8][4]) {
  #pragma unroll
  for (int im = 0; im < 4; ++im) {
    #pragma unroll
    for (int in_ = 0; in_ < 2; ++in_) {
      const int mi = MH * 4 + im, ni = NH * 2 + in_;
      acc[mi][ni] = __builtin_amdgcn_mfma_f32_16x16x32_bf16(af[im][0], bf[ni][0], acc[mi][ni], 0, 0, 0);
      acc[mi][ni] = __builtin_amdgcn_mfma_f32_16x16x32_bf16(af[im][1], bf[ni][1], acc[mi][ni], 0, 0, 0);
    }
  }
}

template<bool ADD_BIAS, bool OUT_F32>
__global__ __launch_bounds__(512, 1)
void gemm256_nt(const unsigned short* __restrict__ A,
                const unsigned short* __restrict__ B,
                const float* __restrict__ bias,
                void* __restrict__ Cout,
                int M, int N, int K) {
  __shared__ unsigned short ldsA[2][2][128 * 64];   // 64 KB
  __shared__ unsigned short ldsB[2][2][128 * 64];   // 64 KB

  const int tid  = threadIdx.x;
  const int wave = tid >> 6;
  const int lane = tid & 63;
  const int wm = wave >> 2;      // 0..1
  const int wn = wave & 3;       // 0..3

  // T1: bijective XCD swizzle (grid size is a multiple of 8 for our shapes)
  const int nwg = gridDim.x;
  const int cpx = nwg >> 3;
  const int bid = blockIdx.x;
  const int swz = (bid & 7) * cpx + (bid >> 3);
  const int ntn = N >> 8;
  const int tm = swz / ntn, tn = swz % ntn;
  const size_t rowBase = (size_t)tm * 256;
  const size_t colBase = (size_t)tn * 256;

  // staging source (pre-swizzled global address; LDS dest linear)
  const int srow  = wave * 8 + (lane >> 3);            // 0..63
  const int sslot = (lane & 7) ^ (lane >> 3);          // inverse swizzle
  const unsigned short* gA = A + (rowBase + srow) * (size_t)K + sslot * 8;
  const unsigned short* gB = B + (colBase + srow) * (size_t)K + sslot * 8;

  // fragment-read per-lane offsets (shorts), swizzled
  const int fr = lane & 15;
  const int kq = lane >> 4;
  const int cA0 = fr * 64 + ((kq)     ^ (fr & 7)) * 8;   // kk=0 slots 0..3
  const int cA1 = fr * 64 + ((4 + kq) ^ (fr & 7)) * 8;   // kk=1 slots 4..7

  f32x4 acc[8][4] = {};
  short8 bf[4][2];

#define STAGE_A(kt, h, BUFI) do { \
    const unsigned short* _g = gA + ((size_t)((h) * 128)) * K + (size_t)(kt) * 64; \
    unsigned short* _l = &ldsA[BUFI][h][wave * 512]; \
    gload_lds16(_g, _l); \
    gload_lds16(_g + (size_t)64 * K, _l + 4096); \
  } while (0)

#define STAGE_B(kt, h, BUFI) do { \
    const unsigned short* _g = gB + ((size_t)((h) * 128)) * K + (size_t)(kt) * 64; \
    unsigned short* _l = &ldsB[BUFI][h][wave * 512]; \
    gload_lds16(_g, _l); \
    gload_lds16(_g + (size_t)64 * K, _l + 4096); \
  } while (0)

#define PHASE(BUFI, MH, NH, LOADB_STMT, STAGE_STMT, WAIT_STMT) do { \
    short8 af[4][2]; \
    load_a<MH>(af, &ldsA[BUFI][wm][0], cA0, cA1); \
    LOADB_STMT; \
    STAGE_STMT; \
    WAIT_STMT; \
    asm volatile("" ::: "memory"); \
    __builtin_amdgcn_s_barrier(); \
    asm volatile("s_waitcnt lgkmcnt(0)" ::: "memory"); \
    __builtin_amdgcn_s_setprio(1); \
    mma16<MH, NH>(af, bf, acc); \
    __builtin_amdgcn_s_setprio(0); \
    asm volatile("" ::: "memory"); \
    __builtin_amdgcn_s_barrier(); \
    asm volatile("" ::: "memory"); \
  } while (0)

#define LOADB0 load_b(bf, &ldsB[0][wn >> 1][(wn & 1) * 4096], cA0, cA1)
#define LOADB1 load_b(bf, &ldsB[1][wn >> 1][(wn & 1) * 4096], cA0, cA1)
#define NOOP ((void)0)
#define WAIT4 asm volatile("s_waitcnt vmcnt(4)" ::: "memory")
#define WAIT0 asm volatile("s_waitcnt vmcnt(0)" ::: "memory")

  const int nIter = K >> 7;   // K/128; requires K >= 256

  // prologue: B(0), A(0), B(1); wait oldest 8 (B0,A0) landed
  STAGE_B(0, 0, 0); STAGE_B(0, 1, 0);
  STAGE_A(0, 0, 0); STAGE_A(0, 1, 0);
  STAGE_B(1, 0, 1); STAGE_B(1, 1, 1);
  WAIT4;
  asm volatile("" ::: "memory");
  __builtin_amdgcn_s_barrier();
  asm volatile("" ::: "memory");

  for (int i = 0; i < nIter - 1; ++i) {
    const int T = 2 * i;
    PHASE(0, 0, 0, LOADB0, STAGE_A(T + 1, 0, 1), NOOP);
    PHASE(0, 1, 0, NOOP,   STAGE_A(T + 1, 1, 1), NOOP);
    PHASE(0, 0, 1, NOOP,   STAGE_B(T + 2, 0, 0), NOOP);
    PHASE(0, 1, 1, NOOP,   STAGE_B(T + 2, 1, 0), WAIT4);
    PHASE(1, 0, 0, LOADB1, STAGE_A(T + 2, 0, 0), NOOP);
    PHASE(1, 1, 0, NOOP,   STAGE_A(T + 2, 1, 0), NOOP);
    PHASE(1, 0, 1, NOOP,   STAGE_B(T + 3, 0, 1), NOOP);
    PHASE(1, 1, 1, NOOP,   STAGE_B(T + 3, 1, 1), WAIT4);
  }
  {
    const int T = 2 * (nIter - 1);
    PHASE(0, 0, 0, LOADB0, STAGE_A(T + 1, 0, 1), NOOP);
    PHASE(0, 1, 0, NOOP,   STAGE_A(T + 1, 1, 1), NOOP);
    PHASE(0, 0, 1, NOOP,   NOOP,                 NOOP);
    PHASE(0, 1, 1, NOOP,   NOOP,                 WAIT0);
    PHASE(1, 0, 0, LOADB1, NOOP,                 NOOP);
    PHASE(1, 1, 0, NOOP,   NOOP,                 NOOP);
    PHASE(1, 0, 1, NOOP,   NOOP,                 NOOP);
    PHASE(1, 1, 1, NOOP,   NOOP,                 NOOP);
  }

#undef STAGE_A
#undef STAGE_B
#undef PHASE
#undef LOADB0
#undef LOADB1
#undef NOOP
#undef WAIT4
#undef WAIT0

  // epilogue: C/D layout col=lane&15, row=(lane>>4)*4+j
  const int orow = (lane >> 4) * 4;
  const int ocol = lane & 15;
  #pragma unroll
  for (int mi = 0; mi < 8; ++mi) {
    #pragma unroll
    for (int ni = 0; ni < 4; ++ni) {
      size_t r0 = rowBase + wm * 128 + mi * 16 + orow;
      size_t c  = colBase + wn * 64 + ni * 16 + ocol;
      float bv_ = ADD_BIAS ? bias[c] : 0.f;
      #pragma unroll
      for (int j = 0; j < 4; ++j) {
        float v = acc[mi][ni][j] + bv_;
        if (OUT_F32) ((float*)Cout)[(r0 + j) * (size_t)N + c] = v;
        else         ((unsigned short*)Cout)[(r0 + j) * (size_t)N + c] = bf16r(v);
      }
    }
  }
}

// ---------- launch ----------

extern "C" void kernel_launch(void* const* d_in, const int* in_sizes, int n_in,
                              void* d_out, int out_size, void* d_ws, size_t ws_size,
                              hipStream_t stream) {
  const float* x       = (const float*)d_in[0];
  const float* q_w     = (const float*)d_in[1];
  const float* q_b     = (const float*)d_in[2];
  const float* k_cache = (const float*)d_in[3];
  const float* v_cache = (const float*)d_in[4];
  const float* out_w   = (const float*)d_in[5];
  const float* out_b   = (const float*)d_in[6];
  float* out = (float*)d_out;

  const int M = 8192, H = 4096;

  char* ws = (char*)d_ws;
  size_t off = 0;
  unsigned short* x_bf    = (unsigned short*)(ws + off); off += (size_t)M * H * 2;
  unsigned short* attn_bf = x_bf;
  unsigned short* qw_bf   = (unsigned short*)(ws + off); off += (size_t)H * H * 2;
  unsigned short* outw_bf = (unsigned short*)(ws + off); off += (size_t)H * H * 2;
  unsigned short* kpad    = (unsigned short*)(ws + off); off += (size_t)128 * H * 2;
  unsigned short* vt      = (unsigned short*)(ws + off); off += (size_t)H * 128 * 2;
  unsigned short* q_bf    = (unsigned short*)(ws + off); off += (size_t)M * H * 2;
  float*          S       = (float*)(ws + off);          off += (size_t)M * 128 * 4;
  unsigned short* W       = (unsigned short*)(ws + off); off += (size_t)M * 128 * 2;
  if (ws_size < off) { fprintf(stderr, "ws too small: need %zu have %zu\n", off, ws_size); return; }

  // 1) conversions / layout builds
  cvt_f32_bf16<<<2048, 256, 0, stream>>>(x, x_bf, M * H / 4);
  cvt_f32_bf16<<<1024, 256, 0, stream>>>(q_w, qw_bf, H * H / 4);
  cvt_f32_bf16<<<1024, 256, 0, stream>>>(out_w, outw_bf, H * H / 4);
  build_kpad<<<2048, 256, 0, stream>>>(k_cache, kpad);
  build_vt<<<2048, 256, 0, stream>>>(v_cache, vt);

  // 2) q = x @ q_w^T + q_b -> bf16   (256^2 8-phase)
  gemm256_nt<true, false><<<dim3((M / 256) * (H / 256)), 512, 0, stream>>>(x_bf, qw_bf, q_b, q_bf, M, H, H);

  // 3) S = q @ kpad^T (fp32)
  gemm_nt<false, true><<<dim3(1, M / 128), 256, 0, stream>>>(q_bf, kpad, nullptr, S, M, 128, H);

  // 4) softmax
  softmax_rows<<<M / 4, 256, 0, stream>>>(S, W, M);

  // 5) attn = W @ vt^T -> bf16
  gemm_nt<false, false><<<dim3(H / 128, M / 128), 256, 0, stream>>>(W, vt, nullptr, attn_bf, M, H, 128);

  // 6) out = attn @ out_w^T + out_b -> fp32   (256^2 8-phase)
  gemm256_nt<true, true><<<dim3((M / 256) * (H / 256)), 512, 0, stream>>>(attn_bf, outw_bf, out_b, out, M, H, H);
}

// Round 3
// 655.672 us; speedup vs baseline: 1.1755x; 1.0557x over previous
//
#include <hip/hip_runtime.h>
#include <cstdio>

typedef __attribute__((ext_vector_type(8))) short short8;
typedef __attribute__((ext_vector_type(4))) float f32x4;

// ---------- helpers ----------

__device__ __forceinline__ unsigned short bf16r(float f) {
  union { float f; unsigned int u; } x; x.f = f;
  unsigned int r = x.u + 0x7fffu + ((x.u >> 16) & 1u);
  return (unsigned short)(r >> 16);
}

__device__ __forceinline__ void gload_lds16(const void* g, void* l) {
  __builtin_amdgcn_global_load_lds((const __attribute__((address_space(1))) void*)g,
                                   (__attribute__((address_space(3))) void*)l,
                                   16, 0, 0);
}

// ---------- conversion kernels ----------

__global__ void cvt_f32_bf16(const float* __restrict__ in, unsigned short* __restrict__ out, int n4) {
  int i = blockIdx.x * blockDim.x + threadIdx.x;
  int stride = gridDim.x * blockDim.x;
  for (; i < n4; i += stride) {
    float4 v = reinterpret_cast<const float4*>(in)[i];
    ushort4 o;
    o.x = bf16r(v.x); o.y = bf16r(v.y); o.z = bf16r(v.z); o.w = bf16r(v.w);
    reinterpret_cast<ushort4*>(out)[i] = o;
  }
}

__global__ void build_kpad(const float* __restrict__ kc, unsigned short* __restrict__ kpad) {
  int idx = blockIdx.x * blockDim.x + threadIdx.x;
  if (idx >= 128 * 4096) return;
  int row = idx >> 12;
  float v = 0.f;
  if (row < 100) v = kc[idx];
  kpad[idx] = bf16r(v);
}

__global__ void build_vt(const float* __restrict__ vc, unsigned short* __restrict__ vt) {
  int idx = blockIdx.x * blockDim.x + threadIdx.x;
  if (idx >= 128 * 4096) return;
  int l = idx >> 12;
  int h = idx & 4095;
  float v = 0.f;
  if (l < 100) v = vc[idx];
  vt[(size_t)h * 128 + l] = bf16r(v);
}

// ---------- softmax ----------

__global__ void softmax_rows(const float* __restrict__ S, unsigned short* __restrict__ W, int rows) {
  int wave = threadIdx.x >> 6;
  int lane = threadIdx.x & 63;
  int row = blockIdx.x * (blockDim.x >> 6) + wave;
  if (row >= rows) return;
  const float scale = 0.088388347648318447f;   // 1/sqrt(128)
  float2 v = reinterpret_cast<const float2*>(S + (size_t)row * 128)[lane];
  int c0 = lane * 2, c1 = c0 + 1;
  float s0 = (c0 <= 100) ? v.x * scale : -1e30f;
  float s1 = (c1 <= 100) ? v.y * scale : -1e30f;
  float m = fmaxf(s0, s1);
  #pragma unroll
  for (int off = 1; off < 64; off <<= 1) m = fmaxf(m, __shfl_xor(m, off));
  float e0 = (c0 <= 100) ? __expf(s0 - m) : 0.f;
  float e1 = (c1 <= 100) ? __expf(s1 - m) : 0.f;
  float sum = e0 + e1;
  #pragma unroll
  for (int off = 1; off < 64; off <<= 1) sum += __shfl_xor(sum, off);
  float inv = 1.f / sum;
  ushort2 o;
  o.x = bf16r(e0 * inv);
  o.y = bf16r(e1 * inv);
  reinterpret_cast<ushort2*>(W + (size_t)row * 128)[lane] = o;
}

// ---------- m97-style 128^2 NT GEMM (kept for S-GEMM N=128 and PV-GEMM K=128) ----------

template<bool ADD_BIAS, bool OUT_F32>
__global__ void gemm_nt(const unsigned short* __restrict__ A,
                        const unsigned short* __restrict__ B,
                        const float* __restrict__ bias,
                        void* __restrict__ Cout,
                        int M, int N, int K) {
  __shared__ unsigned short As[128][32];
  __shared__ unsigned short Bs[128][32];

  const int tid  = threadIdx.x;
  const int wave = tid >> 6;
  const int lane = tid & 63;
  const int wm = wave >> 1;
  const int wn = wave & 1;
  const size_t rowA0 = (size_t)blockIdx.y * 128;
  const size_t colB0 = (size_t)blockIdx.x * 128;

  f32x4 acc[4][4] = {};

  const int sr = wave * 16 + (lane >> 2);
  const int sc = (lane & 3) << 3;

  const unsigned short* Ap0 = A + (rowA0 + sr) * K + sc;
  const unsigned short* Ap1 = A + (rowA0 + 64 + sr) * K + sc;
  const unsigned short* Bp0 = B + (colB0 + sr) * K + sc;
  const unsigned short* Bp1 = B + (colB0 + 64 + sr) * K + sc;
  unsigned short* AsD0 = &As[wave * 16][0];
  unsigned short* AsD1 = &As[64 + wave * 16][0];
  unsigned short* BsD0 = &Bs[wave * 16][0];
  unsigned short* BsD1 = &Bs[64 + wave * 16][0];

  const int fr = lane & 15;
  const int fk = (lane >> 4) << 3;

  for (int k0 = 0; k0 < K; k0 += 32) {
    gload_lds16(Ap0 + k0, AsD0);
    gload_lds16(Ap1 + k0, AsD1);
    gload_lds16(Bp0 + k0, BsD0);
    gload_lds16(Bp1 + k0, BsD1);
    __syncthreads();

    short8 av[4], bv[4];
    #pragma unroll
    for (int mi = 0; mi < 4; ++mi)
      av[mi] = *reinterpret_cast<const short8*>(&As[wm * 64 + mi * 16 + fr][fk]);
    #pragma unroll
    for (int ni = 0; ni < 4; ++ni)
      bv[ni] = *reinterpret_cast<const short8*>(&Bs[wn * 64 + ni * 16 + fr][fk]);
    #pragma unroll
    for (int mi = 0; mi < 4; ++mi)
      #pragma unroll
      for (int ni = 0; ni < 4; ++ni)
        acc[mi][ni] = __builtin_amdgcn_mfma_f32_16x16x32_bf16(av[mi], bv[ni], acc[mi][ni], 0, 0, 0);
    __syncthreads();
  }

  const int orow = (lane >> 4) * 4;
  const int ocol = lane & 15;
  #pragma unroll
  for (int mi = 0; mi < 4; ++mi) {
    #pragma unroll
    for (int ni = 0; ni < 4; ++ni) {
      size_t r0 = rowA0 + wm * 64 + mi * 16 + orow;
      size_t c  = colB0 + wn * 64 + ni * 16 + ocol;
      float bv_ = ADD_BIAS ? bias[c] : 0.f;
      #pragma unroll
      for (int j = 0; j < 4; ++j) {
        float v = acc[mi][ni][j] + bv_;
        if (OUT_F32) ((float*)Cout)[(r0 + j) * (size_t)N + c] = v;
        else         ((unsigned short*)Cout)[(r0 + j) * (size_t)N + c] = bf16r(v);
      }
    }
  }
}

// ---------- 256^2 8-phase NT GEMM v2: one-read-per-frag quadrant schedule ----------
// BM=BN=256, iteration = 2 K-tiles of BK=64 (buf0, buf1), 8 waves (2M x 4N),
// per-wave output 128x64, acc[8][4] f32x4 (128 VGPR).
// Per K-tile: 4 quadrant phases (m0n0, m0n1, m1n1, m1n0):
//   reads 12 (A(m0)8 + B(n0)4) / 4 (B(n1)) / 8 (A(m1)) / 0  = 24/K-tile (was 40).
//   a[4][2] holds the current m-half (carried 2 phases); bq[2][2][2] holds both
//   n-halves for the whole K-tile.
// Stage schedule (2 global_load_lds per phase, region staged only after its last read):
//   ph0: A(T+1)[0,1]  ph1: A(T+1)[2,3]  ph2: B(T+2)[0,1]  ph3: B(T+2)[2,3] +vmcnt(4)
//   ph4: A(T+2)[0,1]  ph5: A(T+2)[2,3]  ph6: B(T+3)[0,1]  ph7: B(T+3)[2,3] +vmcnt(4)
// vmcnt(4) at ph3 drains tile T+1 (read at ph4-6); at ph7 drains tile T+2 (read next ph0-2).
// Uniform loop: stage tile indices clamped to last tile; clamped stages only touch
// regions after their final read, so no epilogue peel is needed.
// Swizzle: 16B slot s of row r stored at slot s^(r&7); linear gload_lds dest +
// inverse-permuted global source; XOR applied on ds_read addresses.

template<bool ADD_BIAS, bool OUT_F32>
__global__ __launch_bounds__(512, 1)
void gemm256_nt(const unsigned short* __restrict__ A,
                const unsigned short* __restrict__ B,
                const float* __restrict__ bias,
                void* __restrict__ Cout,
                int M, int N, int K) {
  __shared__ unsigned short ldsA[2][2][128 * 64];   // [buf][half][row*64+col], 64 KB
  __shared__ unsigned short ldsB[2][2][128 * 64];   // 64 KB

  const int tid  = threadIdx.x;
  const int wave = tid >> 6;
  const int lane = tid & 63;
  const int wm = wave >> 2;      // 0..1
  const int wn = wave & 3;       // 0..3

  // T1: bijective XCD swizzle (grid multiple of 8 for our shapes)
  const int nwg = gridDim.x;
  const int cpx = nwg >> 3;
  const int bid = blockIdx.x;
  const int swz = (bid & 7) * cpx + (bid >> 3);
  const int ntn = N >> 8;
  const int tm = swz / ntn, tn = swz % ntn;
  const size_t rowBase = (size_t)tm * 256;
  const size_t colBase = (size_t)tn * 256;

  // staging: linear LDS dest (wave*8 rows), inverse-swizzled global source slot
  const int srow  = wave * 8 + (lane >> 3);            // 0..63 within a 64-row block
  const int sslot = (lane & 7) ^ (lane >> 3);
  const unsigned short* gA = A + (rowBase + srow) * (size_t)K + sslot * 8;
  const unsigned short* gB = B + (colBase + srow) * (size_t)K + sslot * 8;

  // fragment-read offsets (shorts) within a [row][64] half, swizzled
  const int fr = lane & 15;
  const int kq = lane >> 4;
  const int cA0 = fr * 64 + ((kq)     ^ (fr & 7)) * 8;   // kk=0
  const int cA1 = fr * 64 + ((4 + kq) ^ (fr & 7)) * 8;   // kk=1

  f32x4 acc[8][4] = {};
  short8 a[4][2];        // current m-half A frags
  short8 bq[2][2][2];    // [nq][in][kk] B frags for both n-halves of current K-tile

  // stage issue j (j=0..3) of tile kt: rows j*64..j*64+63 -> lds[buf][j>>1][(j&1)*64 rows]
#define STA(kt, j, BUF) gload_lds16(gA + (size_t)((j) * 64) * K + (size_t)(kt) * 64, \
                                    &ldsA[BUF][(j) >> 1][((j) & 1) * 4096 + wave * 512])
#define STB(kt, j, BUF) gload_lds16(gB + (size_t)((j) * 64) * K + (size_t)(kt) * 64, \
                                    &ldsB[BUF][(j) >> 1][((j) & 1) * 4096 + wave * 512])

#define DSRD_A(BUF, MQ) do { \
    _Pragma("unroll") \
    for (int im = 0; im < 4; ++im) { \
      const unsigned short* _b = &ldsA[BUF][wm][(MQ) * 4096 + im * 1024]; \
      a[im][0] = *reinterpret_cast<const short8*>(_b + cA0); \
      a[im][1] = *reinterpret_cast<const short8*>(_b + cA1); \
    } } while (0)

#define DSRD_B(BUF, NQ) do { \
    _Pragma("unroll") \
    for (int in_ = 0; in_ < 2; ++in_) { \
      const unsigned short* _b = &ldsB[BUF][wn >> 1][(wn & 1) * 4096 + (NQ) * 2048 + in_ * 1024]; \
      bq[NQ][in_][0] = *reinterpret_cast<const short8*>(_b + cA0); \
      bq[NQ][in_][1] = *reinterpret_cast<const short8*>(_b + cA1); \
    } } while (0)

#define MMA(MQ, NQ) do { \
    _Pragma("unroll") \
    for (int im = 0; im < 4; ++im) { \
      _Pragma("unroll") \
      for (int in_ = 0; in_ < 2; ++in_) { \
        acc[(MQ) * 4 + im][(NQ) * 2 + in_] = __builtin_amdgcn_mfma_f32_16x16x32_bf16( \
            a[im][0], bq[NQ][in_][0], acc[(MQ) * 4 + im][(NQ) * 2 + in_], 0, 0, 0); \
        acc[(MQ) * 4 + im][(NQ) * 2 + in_] = __builtin_amdgcn_mfma_f32_16x16x32_bf16( \
            a[im][1], bq[NQ][in_][1], acc[(MQ) * 4 + im][(NQ) * 2 + in_], 0, 0, 0); \
      } } } while (0)

#define PH(MQ, NQ, PRE) do { \
    PRE \
    asm volatile("" ::: "memory"); \
    __builtin_amdgcn_s_barrier(); \
    asm volatile("s_waitcnt lgkmcnt(0)" ::: "memory"); \
    __builtin_amdgcn_s_setprio(1); \
    MMA(MQ, NQ); \
    __builtin_amdgcn_s_setprio(0); \
    asm volatile("" ::: "memory"); \
    __builtin_amdgcn_s_barrier(); \
    asm volatile("" ::: "memory"); \
  } while (0)

#define LGKM8 asm volatile("s_waitcnt lgkmcnt(8)" ::: "memory")
#define WAIT4 asm volatile("s_waitcnt vmcnt(4)" ::: "memory")

  const int nIter = K >> 7;          // iterations of 2 K-tiles
  const int tmax  = (K >> 6) - 1;    // last K-tile index

  // prologue: B(0),A(0) (to be drained), B(1) (left in flight); matches steady state
  #pragma unroll
  for (int j = 0; j < 4; ++j) STB(0, j, 0);
  #pragma unroll
  for (int j = 0; j < 4; ++j) STA(0, j, 0);
  #pragma unroll
  for (int j = 0; j < 4; ++j) STB(1, j, 1);
  WAIT4;
  asm volatile("" ::: "memory");
  __builtin_amdgcn_s_barrier();
  asm volatile("" ::: "memory");

  for (int i = 0; i < nIter; ++i) {
    const int T  = 2 * i;
    const int t2 = (T + 2 > tmax) ? tmax : T + 2;
    const int t3 = (T + 3 > tmax) ? tmax : T + 3;

    PH(0, 0, { DSRD_A(0, 0); DSRD_B(0, 0); STA(T + 1, 0, 1); STA(T + 1, 1, 1); LGKM8; });
    PH(0, 1, { DSRD_B(0, 1);               STA(T + 1, 2, 1); STA(T + 1, 3, 1); });
    PH(1, 1, { DSRD_A(0, 1);               STB(t2, 0, 0);    STB(t2, 1, 0); });
    PH(1, 0, {                             STB(t2, 2, 0);    STB(t2, 3, 0);    WAIT4; });
    PH(0, 0, { DSRD_A(1, 0); DSRD_B(1, 0); STA(t2, 0, 0);    STA(t2, 1, 0);    LGKM8; });
    PH(0, 1, { DSRD_B(1, 1);               STA(t2, 2, 0);    STA(t2, 3, 0); });
    PH(1, 1, { DSRD_A(1, 1);               STB(t3, 0, 1);    STB(t3, 1, 1); });
    PH(1, 0, {                             STB(t3, 2, 1);    STB(t3, 3, 1);    WAIT4; });
  }

#undef STA
#undef STB
#undef DSRD_A
#undef DSRD_B
#undef MMA
#undef PH
#undef LGKM8
#undef WAIT4

  // epilogue: C/D layout col=lane&15, row=(lane>>4)*4+j
  const int orow = (lane >> 4) * 4;
  const int ocol = lane & 15;
  #pragma unroll
  for (int mi = 0; mi < 8; ++mi) {
    #pragma unroll
    for (int ni = 0; ni < 4; ++ni) {
      size_t r0 = rowBase + wm * 128 + mi * 16 + orow;
      size_t c  = colBase + wn * 64 + ni * 16 + ocol;
      float bv_ = ADD_BIAS ? bias[c] : 0.f;
      #pragma unroll
      for (int j = 0; j < 4; ++j) {
        float v = acc[mi][ni][j] + bv_;
        if (OUT_F32) ((float*)Cout)[(r0 + j) * (size_t)N + c] = v;
        else         ((unsigned short*)Cout)[(r0 + j) * (size_t)N + c] = bf16r(v);
      }
    }
  }
}

// ---------- launch ----------

extern "C" void kernel_launch(void* const* d_in, const int* in_sizes, int n_in,
                              void* d_out, int out_size, void* d_ws, size_t ws_size,
                              hipStream_t stream) {
  const float* x       = (const float*)d_in[0];
  const float* q_w     = (const float*)d_in[1];
  const float* q_b     = (const float*)d_in[2];
  const float* k_cache = (const float*)d_in[3];
  const float* v_cache = (const float*)d_in[4];
  const float* out_w   = (const float*)d_in[5];
  const float* out_b   = (const float*)d_in[6];
  float* out = (float*)d_out;

  const int M = 8192, H = 4096;

  char* ws = (char*)d_ws;
  size_t off = 0;
  unsigned short* x_bf    = (unsigned short*)(ws + off); off += (size_t)M * H * 2;
  unsigned short* attn_bf = x_bf;
  unsigned short* qw_bf   = (unsigned short*)(ws + off); off += (size_t)H * H * 2;
  unsigned short* outw_bf = (unsigned short*)(ws + off); off += (size_t)H * H * 2;
  unsigned short* kpad    = (unsigned short*)(ws + off); off += (size_t)128 * H * 2;
  unsigned short* vt      = (unsigned short*)(ws + off); off += (size_t)H * 128 * 2;
  unsigned short* q_bf    = (unsigned short*)(ws + off); off += (size_t)M * H * 2;
  float*          S       = (float*)(ws + off);          off += (size_t)M * 128 * 4;
  unsigned short* W       = (unsigned short*)(ws + off); off += (size_t)M * 128 * 2;
  if (ws_size < off) { fprintf(stderr, "ws too small: need %zu have %zu\n", off, ws_size); return; }

  // 1) conversions / layout builds
  cvt_f32_bf16<<<2048, 256, 0, stream>>>(x, x_bf, M * H / 4);
  cvt_f32_bf16<<<1024, 256, 0, stream>>>(q_w, qw_bf, H * H / 4);
  cvt_f32_bf16<<<1024, 256, 0, stream>>>(out_w, outw_bf, H * H / 4);
  build_kpad<<<2048, 256, 0, stream>>>(k_cache, kpad);
  build_vt<<<2048, 256, 0, stream>>>(v_cache, vt);

  // 2) q = x @ q_w^T + q_b -> bf16   (256^2 8-phase v2)
  gemm256_nt<true, false><<<dim3((M / 256) * (H / 256)), 512, 0, stream>>>(x_bf, qw_bf, q_b, q_bf, M, H, H);

  // 3) S = q @ kpad^T (fp32)
  gemm_nt<false, true><<<dim3(1, M / 128), 256, 0, stream>>>(q_bf, kpad, nullptr, S, M, 128, H);

  // 4) softmax
  softmax_rows<<<M / 4, 256, 0, stream>>>(S, W, M);

  // 5) attn = W @ vt^T -> bf16
  gemm_nt<false, false><<<dim3(H / 128, M / 128), 256, 0, stream>>>(W, vt, nullptr, attn_bf, M, H, 128);

  // 6) out = attn @ out_w^T + out_b -> fp32   (256^2 8-phase v2)
  gemm256_nt<true, true><<<dim3((M / 256) * (H / 256)), 512, 0, stream>>>(attn_bf, outw_bf, out_b, out, M, H, H);
}

// Round 4
// 416.144 us; speedup vs baseline: 1.8521x; 1.5756x over previous
//
#include <hip/hip_runtime.h>
#include <cstdio>

typedef __attribute__((ext_vector_type(8))) short short8;
typedef __attribute__((ext_vector_type(4))) float f32x4;

// ---------- helpers ----------

__device__ __forceinline__ unsigned short bf16r(float f) {
  union { float f; unsigned int u; } x; x.f = f;
  unsigned int r = x.u + 0x7fffu + ((x.u >> 16) & 1u);
  return (unsigned short)(r >> 16);
}

__device__ __forceinline__ float bf16f(unsigned short h) {
  union { unsigned int u; float f; } x; x.u = ((unsigned int)h) << 16;
  return x.f;
}

__device__ __forceinline__ void gload_lds16(const void* g, void* l) {
  __builtin_amdgcn_global_load_lds((const __attribute__((address_space(1))) void*)g,
                                   (__attribute__((address_space(3))) void*)l,
                                   16, 0, 0);
}

// ---------- conversion kernels ----------

__global__ void cvt_f32_bf16(const float* __restrict__ in, unsigned short* __restrict__ out, int n4) {
  int i = blockIdx.x * blockDim.x + threadIdx.x;
  int stride = gridDim.x * blockDim.x;
  for (; i < n4; i += stride) {
    float4 v = reinterpret_cast<const float4*>(in)[i];
    ushort4 o;
    o.x = bf16r(v.x); o.y = bf16r(v.y); o.z = bf16r(v.z); o.w = bf16r(v.w);
    reinterpret_cast<ushort4*>(out)[i] = o;
  }
}

// src [100][4096] f32 -> dst [128][4096] bf16, rows >=100 zero (used for K and V)
__global__ void build_pad128(const float* __restrict__ src, unsigned short* __restrict__ dst) {
  int idx = blockIdx.x * blockDim.x + threadIdx.x;
  if (idx >= 128 * 4096) return;
  int row = idx >> 12;
  float v = 0.f;
  if (row < 100) v = src[idx];
  dst[idx] = bf16r(v);
}

// ---------- split-K 128x128-tile NT GEMM partial: Cpart[ks] = A[:,ks-chunk] @ B[:,ks-chunk]^T ----------
// N is fixed at 128 (full B). grid = (KS, M/128). Cpart layout [KS][M][128] f32.

__global__ void gemm_nt_splitk(const unsigned short* __restrict__ A,
                               const unsigned short* __restrict__ B,
                               float* __restrict__ Cpart,
                               int M, int K, int kchunk) {
  __shared__ unsigned short As[128][32];
  __shared__ unsigned short Bs[128][32];

  const int tid  = threadIdx.x;
  const int wave = tid >> 6;
  const int lane = tid & 63;
  const int wm = wave >> 1;
  const int wn = wave & 1;
  const size_t rowA0 = (size_t)blockIdx.y * 128;
  const int k0base = blockIdx.x * kchunk;

  f32x4 acc[4][4] = {};

  const int sr = wave * 16 + (lane >> 2);
  const int sc = (lane & 3) << 3;

  const unsigned short* Ap0 = A + (rowA0 + sr) * (size_t)K + k0base + sc;
  const unsigned short* Ap1 = A + (rowA0 + 64 + sr) * (size_t)K + k0base + sc;
  const unsigned short* Bp0 = B + (size_t)sr * K + k0base + sc;
  const unsigned short* Bp1 = B + (size_t)(64 + sr) * K + k0base + sc;
  unsigned short* AsD0 = &As[wave * 16][0];
  unsigned short* AsD1 = &As[64 + wave * 16][0];
  unsigned short* BsD0 = &Bs[wave * 16][0];
  unsigned short* BsD1 = &Bs[64 + wave * 16][0];

  const int fr = lane & 15;
  const int fk = (lane >> 4) << 3;

  for (int k0 = 0; k0 < kchunk; k0 += 32) {
    gload_lds16(Ap0 + k0, AsD0);
    gload_lds16(Ap1 + k0, AsD1);
    gload_lds16(Bp0 + k0, BsD0);
    gload_lds16(Bp1 + k0, BsD1);
    __syncthreads();

    short8 av[4], bv[4];
    #pragma unroll
    for (int mi = 0; mi < 4; ++mi)
      av[mi] = *reinterpret_cast<const short8*>(&As[wm * 64 + mi * 16 + fr][fk]);
    #pragma unroll
    for (int ni = 0; ni < 4; ++ni)
      bv[ni] = *reinterpret_cast<const short8*>(&Bs[wn * 64 + ni * 16 + fr][fk]);
    #pragma unroll
    for (int mi = 0; mi < 4; ++mi)
      #pragma unroll
      for (int ni = 0; ni < 4; ++ni)
        acc[mi][ni] = __builtin_amdgcn_mfma_f32_16x16x32_bf16(av[mi], bv[ni], acc[mi][ni], 0, 0, 0);
    __syncthreads();
  }

  float* Cp = Cpart + (size_t)blockIdx.x * M * 128;
  const int orow = (lane >> 4) * 4;
  const int ocol = lane & 15;
  #pragma unroll
  for (int mi = 0; mi < 4; ++mi) {
    #pragma unroll
    for (int ni = 0; ni < 4; ++ni) {
      size_t r0 = rowA0 + wm * 64 + mi * 16 + orow;
      size_t c  = (size_t)wn * 64 + ni * 16 + ocol;
      #pragma unroll
      for (int j = 0; j < 4; ++j)
        Cp[(r0 + j) * 128 + c] = acc[mi][ni][j];
    }
  }
}

// ---------- fused partial-sum + softmax -> duplicated [W|W] bf16 [rows][256] ----------

__global__ void softmax_fused(const float* __restrict__ Spart, unsigned short* __restrict__ W2, int rows) {
  int wave = threadIdx.x >> 6;
  int lane = threadIdx.x & 63;
  int row = blockIdx.x * (blockDim.x >> 6) + wave;
  if (row >= rows) return;
  const float scale = 0.088388347648318447f;   // 1/sqrt(128)
  float sx = 0.f, sy = 0.f;
  #pragma unroll
  for (int ks = 0; ks < 4; ++ks) {
    float2 p = reinterpret_cast<const float2*>(Spart + (size_t)ks * rows * 128 + (size_t)row * 128)[lane];
    sx += p.x; sy += p.y;
  }
  int c0 = lane * 2, c1 = c0 + 1;
  float s0 = (c0 <= 100) ? sx * scale : -1e30f;
  float s1 = (c1 <= 100) ? sy * scale : -1e30f;
  float m = fmaxf(s0, s1);
  #pragma unroll
  for (int off = 1; off < 64; off <<= 1) m = fmaxf(m, __shfl_xor(m, off));
  float e0 = (c0 <= 100) ? __expf(s0 - m) : 0.f;
  float e1 = (c1 <= 100) ? __expf(s1 - m) : 0.f;
  float sum = e0 + e1;
  #pragma unroll
  for (int off = 1; off < 64; off <<= 1) sum += __shfl_xor(sum, off);
  float inv = 1.f / sum;
  ushort2 o;
  o.x = bf16r(e0 * inv);
  o.y = bf16r(e1 * inv);
  reinterpret_cast<ushort2*>(W2 + (size_t)row * 256)[lane] = o;
  reinterpret_cast<ushort2*>(W2 + (size_t)row * 256 + 128)[lane] = o;
}

// ---------- VO reduce: sum 8 partials, split into bf16 hi/lo planes [4096][256] ----------

__global__ void vo_reduce(const float* __restrict__ VOpart, unsigned short* __restrict__ VOT2) {
  int idx = blockIdx.x * blockDim.x + threadIdx.x;   // over 4096*128, idx = o*128 + l
  if (idx >= 4096 * 128) return;
  float s = 0.f;
  #pragma unroll
  for (int ks = 0; ks < 8; ++ks) s += VOpart[(size_t)ks * 4096 * 128 + idx];
  unsigned short hi = bf16r(s);
  unsigned short lo = bf16r(s - bf16f(hi));
  int o = idx >> 7, l = idx & 127;
  VOT2[(size_t)o * 256 + l]       = hi;
  VOT2[(size_t)o * 256 + 128 + l] = lo;
}

// ---------- m97-style 128^2 NT GEMM (final: out = W2 @ VOT2^T + out_b) ----------

template<bool ADD_BIAS, bool OUT_F32>
__global__ void gemm_nt(const unsigned short* __restrict__ A,
                        const unsigned short* __restrict__ B,
                        const float* __restrict__ bias,
                        void* __restrict__ Cout,
                        int M, int N, int K) {
  __shared__ unsigned short As[128][32];
  __shared__ unsigned short Bs[128][32];

  const int tid  = threadIdx.x;
  const int wave = tid >> 6;
  const int lane = tid & 63;
  const int wm = wave >> 1;
  const int wn = wave & 1;
  const size_t rowA0 = (size_t)blockIdx.y * 128;
  const size_t colB0 = (size_t)blockIdx.x * 128;

  f32x4 acc[4][4] = {};

  const int sr = wave * 16 + (lane >> 2);
  const int sc = (lane & 3) << 3;

  const unsigned short* Ap0 = A + (rowA0 + sr) * (size_t)K + sc;
  const unsigned short* Ap1 = A + (rowA0 + 64 + sr) * (size_t)K + sc;
  const unsigned short* Bp0 = B + (colB0 + sr) * (size_t)K + sc;
  const unsigned short* Bp1 = B + (colB0 + 64 + sr) * (size_t)K + sc;
  unsigned short* AsD0 = &As[wave * 16][0];
  unsigned short* AsD1 = &As[64 + wave * 16][0];
  unsigned short* BsD0 = &Bs[wave * 16][0];
  unsigned short* BsD1 = &Bs[64 + wave * 16][0];

  const int fr = lane & 15;
  const int fk = (lane >> 4) << 3;

  for (int k0 = 0; k0 < K; k0 += 32) {
    gload_lds16(Ap0 + k0, AsD0);
    gload_lds16(Ap1 + k0, AsD1);
    gload_lds16(Bp0 + k0, BsD0);
    gload_lds16(Bp1 + k0, BsD1);
    __syncthreads();

    short8 av[4], bv[4];
    #pragma unroll
    for (int mi = 0; mi < 4; ++mi)
      av[mi] = *reinterpret_cast<const short8*>(&As[wm * 64 + mi * 16 + fr][fk]);
    #pragma unroll
    for (int ni = 0; ni < 4; ++ni)
      bv[ni] = *reinterpret_cast<const short8*>(&Bs[wn * 64 + ni * 16 + fr][fk]);
    #pragma unroll
    for (int mi = 0; mi < 4; ++mi)
      #pragma unroll
      for (int ni = 0; ni < 4; ++ni)
        acc[mi][ni] = __builtin_amdgcn_mfma_f32_16x16x32_bf16(av[mi], bv[ni], acc[mi][ni], 0, 0, 0);
    __syncthreads();
  }

  const int orow = (lane >> 4) * 4;
  const int ocol = lane & 15;
  #pragma unroll
  for (int mi = 0; mi < 4; ++mi) {
    #pragma unroll
    for (int ni = 0; ni < 4; ++ni) {
      size_t r0 = rowA0 + wm * 64 + mi * 16 + orow;
      size_t c  = colB0 + wn * 64 + ni * 16 + ocol;
      float bv_ = ADD_BIAS ? bias[c] : 0.f;
      #pragma unroll
      for (int j = 0; j < 4; ++j) {
        float v = acc[mi][ni][j] + bv_;
        if (OUT_F32) ((float*)Cout)[(r0 + j) * (size_t)N + c] = v;
        else         ((unsigned short*)Cout)[(r0 + j) * (size_t)N + c] = bf16r(v);
      }
    }
  }
}

// ---------- 256^2 8-phase NT GEMM v2 (q-proj) — unchanged from round 3 ----------

template<bool ADD_BIAS, bool OUT_F32>
__global__ __launch_bounds__(512, 1)
void gemm256_nt(const unsigned short* __restrict__ A,
                const unsigned short* __restrict__ B,
                const float* __restrict__ bias,
                void* __restrict__ Cout,
                int M, int N, int K) {
  __shared__ unsigned short ldsA[2][2][128 * 64];
  __shared__ unsigned short ldsB[2][2][128 * 64];

  const int tid  = threadIdx.x;
  const int wave = tid >> 6;
  const int lane = tid & 63;
  const int wm = wave >> 2;
  const int wn = wave & 3;

  const int nwg = gridDim.x;
  const int cpx = nwg >> 3;
  const int bid = blockIdx.x;
  const int swz = (bid & 7) * cpx + (bid >> 3);
  const int ntn = N >> 8;
  const int tm = swz / ntn, tn = swz % ntn;
  const size_t rowBase = (size_t)tm * 256;
  const size_t colBase = (size_t)tn * 256;

  const int srow  = wave * 8 + (lane >> 3);
  const int sslot = (lane & 7) ^ (lane >> 3);
  const unsigned short* gA = A + (rowBase + srow) * (size_t)K + sslot * 8;
  const unsigned short* gB = B + (colBase + srow) * (size_t)K + sslot * 8;

  const int fr = lane & 15;
  const int kq = lane >> 4;
  const int cA0 = fr * 64 + ((kq)     ^ (fr & 7)) * 8;
  const int cA1 = fr * 64 + ((4 + kq) ^ (fr & 7)) * 8;

  f32x4 acc[8][4] = {};
  short8 a[4][2];
  short8 bq[2][2][2];

#define STA(kt, j, BUF) gload_lds16(gA + (size_t)((j) * 64) * K + (size_t)(kt) * 64, \
                                    &ldsA[BUF][(j) >> 1][((j) & 1) * 4096 + wave * 512])
#define STB(kt, j, BUF) gload_lds16(gB + (size_t)((j) * 64) * K + (size_t)(kt) * 64, \
                                    &ldsB[BUF][(j) >> 1][((j) & 1) * 4096 + wave * 512])

#define DSRD_A(BUF, MQ) do { \
    _Pragma("unroll") \
    for (int im = 0; im < 4; ++im) { \
      const unsigned short* _b = &ldsA[BUF][wm][(MQ) * 4096 + im * 1024]; \
      a[im][0] = *reinterpret_cast<const short8*>(_b + cA0); \
      a[im][1] = *reinterpret_cast<const short8*>(_b + cA1); \
    } } while (0)

#define DSRD_B(BUF, NQ) do { \
    _Pragma("unroll") \
    for (int in_ = 0; in_ < 2; ++in_) { \
      const unsigned short* _b = &ldsB[BUF][wn >> 1][(wn & 1) * 4096 + (NQ) * 2048 + in_ * 1024]; \
      bq[NQ][in_][0] = *reinterpret_cast<const short8*>(_b + cA0); \
      bq[NQ][in_][1] = *reinterpret_cast<const short8*>(_b + cA1); \
    } } while (0)

#define MMA(MQ, NQ) do { \
    _Pragma("unroll") \
    for (int im = 0; im < 4; ++im) { \
      _Pragma("unroll") \
      for (int in_ = 0; in_ < 2; ++in_) { \
        acc[(MQ) * 4 + im][(NQ) * 2 + in_] = __builtin_amdgcn_mfma_f32_16x16x32_bf16( \
            a[im][0], bq[NQ][in_][0], acc[(MQ) * 4 + im][(NQ) * 2 + in_], 0, 0, 0); \
        acc[(MQ) * 4 + im][(NQ) * 2 + in_] = __builtin_amdgcn_mfma_f32_16x16x32_bf16( \
            a[im][1], bq[NQ][in_][1], acc[(MQ) * 4 + im][(NQ) * 2 + in_], 0, 0, 0); \
      } } } while (0)

#define PH(MQ, NQ, PRE) do { \
    PRE \
    asm volatile("" ::: "memory"); \
    __builtin_amdgcn_s_barrier(); \
    asm volatile("s_waitcnt lgkmcnt(0)" ::: "memory"); \
    __builtin_amdgcn_s_setprio(1); \
    MMA(MQ, NQ); \
    __builtin_amdgcn_s_setprio(0); \
    asm volatile("" ::: "memory"); \
    __builtin_amdgcn_s_barrier(); \
    asm volatile("" ::: "memory"); \
  } while (0)

#define LGKM8 asm volatile("s_waitcnt lgkmcnt(8)" ::: "memory")
#define WAIT4 asm volatile("s_waitcnt vmcnt(4)" ::: "memory")

  const int nIter = K >> 7;
  const int tmax  = (K >> 6) - 1;

  #pragma unroll
  for (int j = 0; j < 4; ++j) STB(0, j, 0);
  #pragma unroll
  for (int j = 0; j < 4; ++j) STA(0, j, 0);
  #pragma unroll
  for (int j = 0; j < 4; ++j) STB(1, j, 1);
  WAIT4;
  asm volatile("" ::: "memory");
  __builtin_amdgcn_s_barrier();
  asm volatile("" ::: "memory");

  for (int i = 0; i < nIter; ++i) {
    const int T  = 2 * i;
    const int t2 = (T + 2 > tmax) ? tmax : T + 2;
    const int t3 = (T + 3 > tmax) ? tmax : T + 3;

    PH(0, 0, { DSRD_A(0, 0); DSRD_B(0, 0); STA(T + 1, 0, 1); STA(T + 1, 1, 1); LGKM8; });
    PH(0, 1, { DSRD_B(0, 1);               STA(T + 1, 2, 1); STA(T + 1, 3, 1); });
    PH(1, 1, { DSRD_A(0, 1);               STB(t2, 0, 0);    STB(t2, 1, 0); });
    PH(1, 0, {                             STB(t2, 2, 0);    STB(t2, 3, 0);    WAIT4; });
    PH(0, 0, { DSRD_A(1, 0); DSRD_B(1, 0); STA(t2, 0, 0);    STA(t2, 1, 0);    LGKM8; });
    PH(0, 1, { DSRD_B(1, 1);               STA(t2, 2, 0);    STA(t2, 3, 0); });
    PH(1, 1, { DSRD_A(1, 1);               STB(t3, 0, 1);    STB(t3, 1, 1); });
    PH(1, 0, {                             STB(t3, 2, 1);    STB(t3, 3, 1);    WAIT4; });
  }

#undef STA
#undef STB
#undef DSRD_A
#undef DSRD_B
#undef MMA
#undef PH
#undef LGKM8
#undef WAIT4

  const int orow = (lane >> 4) * 4;
  const int ocol = lane & 15;
  #pragma unroll
  for (int mi = 0; mi < 8; ++mi) {
    #pragma unroll
    for (int ni = 0; ni < 4; ++ni) {
      size_t r0 = rowBase + wm * 128 + mi * 16 + orow;
      size_t c  = colBase + wn * 64 + ni * 16 + ocol;
      float bv_ = ADD_BIAS ? bias[c] : 0.f;
      #pragma unroll
      for (int j = 0; j < 4; ++j) {
        float v = acc[mi][ni][j] + bv_;
        if (OUT_F32) ((float*)Cout)[(r0 + j) * (size_t)N + c] = v;
        else         ((unsigned short*)Cout)[(r0 + j) * (size_t)N + c] = bf16r(v);
      }
    }
  }
}

// ---------- launch ----------

extern "C" void kernel_launch(void* const* d_in, const int* in_sizes, int n_in,
                              void* d_out, int out_size, void* d_ws, size_t ws_size,
                              hipStream_t stream) {
  const float* x       = (const float*)d_in[0];
  const float* q_w     = (const float*)d_in[1];
  const float* q_b     = (const float*)d_in[2];
  const float* k_cache = (const float*)d_in[3];
  const float* v_cache = (const float*)d_in[4];
  const float* out_w   = (const float*)d_in[5];
  const float* out_b   = (const float*)d_in[6];
  float* out = (float*)d_out;

  const int M = 8192, H = 4096;

  char* ws = (char*)d_ws;
  size_t off = 0;
  unsigned short* x_bf    = (unsigned short*)(ws + off); off += (size_t)M * H * 2;       // 64 MB
  unsigned short* qw_bf   = (unsigned short*)(ws + off); off += (size_t)H * H * 2;       // 32 MB
  unsigned short* outw_bf = (unsigned short*)(ws + off); off += (size_t)H * H * 2;       // 32 MB
  unsigned short* kpad    = (unsigned short*)(ws + off); off += (size_t)128 * H * 2;     // 1 MB
  unsigned short* vpad    = (unsigned short*)(ws + off); off += (size_t)128 * H * 2;     // 1 MB
  unsigned short* q_bf    = (unsigned short*)(ws + off); off += (size_t)M * H * 2;       // 64 MB
  // sub-allocations inside the x_bf region (x_bf dead after q-proj GEMM):
  float*          Spart   = (float*)x_bf;                          // 4*8192*128*4 = 16 MB
  float*          VOpart  = (float*)x_bf;                          // 8*4096*128*4 = 16 MB (after softmax)
  unsigned short* W2      = (unsigned short*)((char*)x_bf + (16u << 20));   // 8192*256*2 = 4 MB
  unsigned short* VOT2    = (unsigned short*)((char*)x_bf + (20u << 20));   // 4096*256*2 = 2 MB
  if (ws_size < off) { fprintf(stderr, "ws too small: need %zu have %zu\n", off, ws_size); return; }

  // 1) conversions / layout builds
  cvt_f32_bf16<<<2048, 256, 0, stream>>>(x, x_bf, M * H / 4);
  cvt_f32_bf16<<<1024, 256, 0, stream>>>(q_w, qw_bf, H * H / 4);
  cvt_f32_bf16<<<1024, 256, 0, stream>>>(out_w, outw_bf, H * H / 4);
  build_pad128<<<2048, 256, 0, stream>>>(k_cache, kpad);
  build_pad128<<<2048, 256, 0, stream>>>(v_cache, vpad);

  // 2) q = x @ q_w^T + q_b -> bf16   (256^2 8-phase)
  gemm256_nt<true, false><<<dim3((M / 256) * (H / 256)), 512, 0, stream>>>(x_bf, qw_bf, q_b, q_bf, M, H, H);

  // 3) S partials = q @ kpad^T, split-K 4 x 1024  (into x_bf region; x dead)
  gemm_nt_splitk<<<dim3(4, M / 128), 256, 0, stream>>>(q_bf, kpad, Spart, M, H, H / 4);

  // 4) softmax (sums partials) -> duplicated [W|W] bf16 [M][256]
  softmax_fused<<<M / 4, 256, 0, stream>>>(Spart, W2, M);

  // 5) VO^T partials = out_w @ vpad^T, split-K 8 x 512  (VOpart aliases Spart; Spart dead)
  gemm_nt_splitk<<<dim3(8, H / 128), 256, 0, stream>>>(outw_bf, vpad, VOpart, H, H, H / 8);

  // 6) reduce partials, split into bf16 hi/lo planes -> VOT2 [4096][256]
  vo_reduce<<<2048, 256, 0, stream>>>(VOpart, VOT2);

  // 7) out = W2 @ VOT2^T + out_b  (K=256: [W|W] x [hi|lo] preserves f32 VO precision)
  gemm_nt<true, true><<<dim3(H / 128, M / 128), 256, 0, stream>>>(W2, VOT2, out_b, out, M, H, 256);
}

// Round 5
// 209.502 us; speedup vs baseline: 3.6789x; 1.9863x over previous
//
#include <hip/hip_runtime.h>
#include <cstdio>

typedef __attribute__((ext_vector_type(8))) short short8;
typedef __attribute__((ext_vector_type(4))) float f32x4;

// ---------- helpers ----------

__device__ __forceinline__ unsigned short bf16r(float f) {
  union { float f; unsigned int u; } x; x.f = f;
  unsigned int r = x.u + 0x7fffu + ((x.u >> 16) & 1u);
  return (unsigned short)(r >> 16);
}

__device__ __forceinline__ float bf16f(unsigned short h) {
  union { unsigned int u; float f; } x; x.u = ((unsigned int)h) << 16;
  return x.f;
}

__device__ __forceinline__ void gload_lds16(const void* g, void* l) {
  __builtin_amdgcn_global_load_lds((const __attribute__((address_space(1))) void*)g,
                                   (__attribute__((address_space(3))) void*)l,
                                   16, 0, 0);
}

// ---------- q_w [4096][4096] f32 -> qwt2 [4096(j)][8192] bf16: cols 0..4095 = hi(q_w^T), 4096.. = lo ----------

__global__ void transpose_hilo(const float* __restrict__ in, unsigned short* __restrict__ out) {
  __shared__ float tile[64][65];
  const int j0 = blockIdx.x * 64, i0 = blockIdx.y * 64;
  const int tx = threadIdx.x & 15, ty = threadIdx.x >> 4;
  #pragma unroll
  for (int w = 0; w < 4; ++w) {
    int r = ty + w * 16;
    float4 v = *reinterpret_cast<const float4*>(in + (size_t)(i0 + r) * 4096 + j0 + tx * 4);
    tile[r][tx * 4 + 0] = v.x; tile[r][tx * 4 + 1] = v.y;
    tile[r][tx * 4 + 2] = v.z; tile[r][tx * 4 + 3] = v.w;
  }
  __syncthreads();
  #pragma unroll
  for (int w = 0; w < 4; ++w) {
    int r = ty + w * 16;   // j offset within tile
    float v0 = tile[tx * 4 + 0][r], v1 = tile[tx * 4 + 1][r];
    float v2 = tile[tx * 4 + 2][r], v3 = tile[tx * 4 + 3][r];
    ushort4 hi, lo;
    hi.x = bf16r(v0); lo.x = bf16r(v0 - bf16f(hi.x));
    hi.y = bf16r(v1); lo.y = bf16r(v1 - bf16f(hi.y));
    hi.z = bf16r(v2); lo.z = bf16r(v2 - bf16f(hi.z));
    hi.w = bf16r(v3); lo.w = bf16r(v3 - bf16f(hi.w));
    *reinterpret_cast<ushort4*>(out + (size_t)(j0 + r) * 8192 + i0 + tx * 4) = hi;
    *reinterpret_cast<ushort4*>(out + (size_t)(j0 + r) * 8192 + 4096 + i0 + tx * 4) = lo;
  }
}

// ---------- k_cache [100][4096] f32 -> kpad2 [128][8192] bf16 duplicated ([kpad|kpad]), rows>=100 zero ----------

__global__ void build_pad_dup(const float* __restrict__ src, unsigned short* __restrict__ dst) {
  int idx = blockIdx.x * blockDim.x + threadIdx.x;   // over 128*4096
  if (idx >= 128 * 4096) return;
  int l = idx >> 12, i = idx & 4095;
  float v = (l < 100) ? src[idx] : 0.f;
  unsigned short b = bf16r(v);
  dst[(size_t)l * 8192 + i] = b;
  dst[(size_t)l * 8192 + 4096 + i] = b;
}

// ---------- v_cache [100][4096] f32 -> vpad [128][4096] bf16, rows>=100 zero ----------

__global__ void build_pad128(const float* __restrict__ src, unsigned short* __restrict__ dst) {
  int idx = blockIdx.x * blockDim.x + threadIdx.x;
  if (idx >= 128 * 4096) return;
  int row = idx >> 12;
  float v = (row < 100) ? src[idx] : 0.f;
  dst[idx] = bf16r(v);
}

// ---------- sbias[l] = q_b . k_cache[l] (f32, exact), 0 for l>=100 ----------

__global__ void kq_bias(const float* __restrict__ kc, const float* __restrict__ qb,
                        float* __restrict__ sbias) {
  int l = blockIdx.x;            // 0..127
  int lane = threadIdx.x;        // 64
  float s = 0.f;
  if (l < 100) {
    for (int i = lane * 4; i < 4096; i += 256) {
      float4 k = *reinterpret_cast<const float4*>(kc + (size_t)l * 4096 + i);
      float4 q = *reinterpret_cast<const float4*>(qb + i);
      s += k.x * q.x + k.y * q.y + k.z * q.z + k.w * q.w;
    }
  }
  #pragma unroll
  for (int off = 1; off < 64; off <<= 1) s += __shfl_xor(s, off);
  if (lane == 0) sbias[l] = s;
}

// ---------- split-K NT GEMM, bf16 A (gload_lds) x bf16 B (gload_lds) -> f32 partials ----------
// grid (KS, Mtiles, Ntiles); Cpart[ks][M][N]; Kstride = row stride of A and B.

__global__ void gemm_ntk_splitk(const unsigned short* __restrict__ A,
                                const unsigned short* __restrict__ B,
                                float* __restrict__ Cpart,
                                int M, int N, int Kstride, int kchunk) {
  __shared__ unsigned short As[128][32];
  __shared__ unsigned short Bs[128][32];

  const int tid = threadIdx.x, wave = tid >> 6, lane = tid & 63;
  const int wm = wave >> 1, wn = wave & 1;
  const size_t rowA0 = (size_t)blockIdx.y * 128;
  const size_t colB0 = (size_t)blockIdx.z * 128;
  const int k0base = blockIdx.x * kchunk;

  f32x4 acc[4][4] = {};

  const int sr = wave * 16 + (lane >> 2);
  const int sc = (lane & 3) << 3;

  const unsigned short* Ap0 = A + (rowA0 + sr) * (size_t)Kstride + k0base + sc;
  const unsigned short* Ap1 = A + (rowA0 + 64 + sr) * (size_t)Kstride + k0base + sc;
  const unsigned short* Bp0 = B + (colB0 + sr) * (size_t)Kstride + k0base + sc;
  const unsigned short* Bp1 = B + (colB0 + 64 + sr) * (size_t)Kstride + k0base + sc;
  unsigned short* AsD0 = &As[wave * 16][0];
  unsigned short* AsD1 = &As[64 + wave * 16][0];
  unsigned short* BsD0 = &Bs[wave * 16][0];
  unsigned short* BsD1 = &Bs[64 + wave * 16][0];

  const int fr = lane & 15;
  const int fk = (lane >> 4) << 3;

  for (int k0 = 0; k0 < kchunk; k0 += 32) {
    gload_lds16(Ap0 + k0, AsD0);
    gload_lds16(Ap1 + k0, AsD1);
    gload_lds16(Bp0 + k0, BsD0);
    gload_lds16(Bp1 + k0, BsD1);
    __syncthreads();

    short8 av[4], bv[4];
    #pragma unroll
    for (int mi = 0; mi < 4; ++mi)
      av[mi] = *reinterpret_cast<const short8*>(&As[wm * 64 + mi * 16 + fr][fk]);
    #pragma unroll
    for (int ni = 0; ni < 4; ++ni)
      bv[ni] = *reinterpret_cast<const short8*>(&Bs[wn * 64 + ni * 16 + fr][fk]);
    #pragma unroll
    for (int mi = 0; mi < 4; ++mi)
      #pragma unroll
      for (int ni = 0; ni < 4; ++ni)
        acc[mi][ni] = __builtin_amdgcn_mfma_f32_16x16x32_bf16(av[mi], bv[ni], acc[mi][ni], 0, 0, 0);
    __syncthreads();
  }

  float* Cp = Cpart + (size_t)blockIdx.x * M * N;
  const int orow = (lane >> 4) * 4;
  const int ocol = lane & 15;
  #pragma unroll
  for (int mi = 0; mi < 4; ++mi) {
    #pragma unroll
    for (int ni = 0; ni < 4; ++ni) {
      size_t r0 = rowA0 + wm * 64 + mi * 16 + orow;
      size_t c  = colB0 + wn * 64 + ni * 16 + ocol;
      #pragma unroll
      for (int j = 0; j < 4; ++j)
        Cp[(r0 + j) * (size_t)N + c] = acc[mi][ni][j];
    }
  }
}

// ---------- split-K NT GEMM, f32 A (reg-staged cvt) x bf16 B (gload_lds) -> f32 partials ----------
// blockIdx.x = composite (ks << ntShift) | ntile; grid (KS<<ntShift, Mtiles, 1).

__global__ void gemm_ntf_splitk(const float* __restrict__ A,
                                const unsigned short* __restrict__ B,
                                float* __restrict__ Cpart,
                                int M, int N, int Kstride, int kchunk, int ntShift) {
  __shared__ unsigned short As[128][32];
  __shared__ unsigned short Bs[128][32];

  const int tid = threadIdx.x, wave = tid >> 6, lane = tid & 63;
  const int wm = wave >> 1, wn = wave & 1;
  const int ks = blockIdx.x >> ntShift;
  const int ntile = blockIdx.x & ((1 << ntShift) - 1);
  const size_t rowA0 = (size_t)blockIdx.y * 128;
  const size_t colB0 = (size_t)ntile * 128;
  const int k0base = ks * kchunk;

  f32x4 acc[4][4] = {};

  // A staging: thread t covers row t>>1, k-half (t&1)*16 (16 f32 -> 16 bf16 per step)
  const int arow = tid >> 1;
  const int ahalf = (tid & 1) * 16;
  const float* Aprow = A + (rowA0 + arow) * (size_t)Kstride + k0base + ahalf;

  const int sr = wave * 16 + (lane >> 2);
  const int sc = (lane & 3) << 3;
  const unsigned short* Bp0 = B + (colB0 + sr) * (size_t)Kstride + k0base + sc;
  const unsigned short* Bp1 = B + (colB0 + 64 + sr) * (size_t)Kstride + k0base + sc;
  unsigned short* BsD0 = &Bs[wave * 16][0];
  unsigned short* BsD1 = &Bs[64 + wave * 16][0];

  const int fr = lane & 15;
  const int fk = (lane >> 4) << 3;

  for (int k0 = 0; k0 < kchunk; k0 += 32) {
    gload_lds16(Bp0 + k0, BsD0);
    gload_lds16(Bp1 + k0, BsD1);
    float4 f0 = *reinterpret_cast<const float4*>(Aprow + k0);
    float4 f1 = *reinterpret_cast<const float4*>(Aprow + k0 + 4);
    float4 f2 = *reinterpret_cast<const float4*>(Aprow + k0 + 8);
    float4 f3 = *reinterpret_cast<const float4*>(Aprow + k0 + 12);
    short8 h0, h1;
    h0[0] = (short)bf16r(f0.x); h0[1] = (short)bf16r(f0.y);
    h0[2] = (short)bf16r(f0.z); h0[3] = (short)bf16r(f0.w);
    h0[4] = (short)bf16r(f1.x); h0[5] = (short)bf16r(f1.y);
    h0[6] = (short)bf16r(f1.z); h0[7] = (short)bf16r(f1.w);
    h1[0] = (short)bf16r(f2.x); h1[1] = (short)bf16r(f2.y);
    h1[2] = (short)bf16r(f2.z); h1[3] = (short)bf16r(f2.w);
    h1[4] = (short)bf16r(f3.x); h1[5] = (short)bf16r(f3.y);
    h1[6] = (short)bf16r(f3.z); h1[7] = (short)bf16r(f3.w);
    *reinterpret_cast<short8*>(&As[arow][ahalf]) = h0;
    *reinterpret_cast<short8*>(&As[arow][ahalf + 8]) = h1;
    __syncthreads();

    short8 av[4], bv[4];
    #pragma unroll
    for (int mi = 0; mi < 4; ++mi)
      av[mi] = *reinterpret_cast<const short8*>(&As[wm * 64 + mi * 16 + fr][fk]);
    #pragma unroll
    for (int ni = 0; ni < 4; ++ni)
      bv[ni] = *reinterpret_cast<const short8*>(&Bs[wn * 64 + ni * 16 + fr][fk]);
    #pragma unroll
    for (int mi = 0; mi < 4; ++mi)
      #pragma unroll
      for (int ni = 0; ni < 4; ++ni)
        acc[mi][ni] = __builtin_amdgcn_mfma_f32_16x16x32_bf16(av[mi], bv[ni], acc[mi][ni], 0, 0, 0);
    __syncthreads();
  }

  float* Cp = Cpart + (size_t)ks * M * N;
  const int orow = (lane >> 4) * 4;
  const int ocol = lane & 15;
  #pragma unroll
  for (int mi = 0; mi < 4; ++mi) {
    #pragma unroll
    for (int ni = 0; ni < 4; ++ni) {
      size_t r0 = rowA0 + wm * 64 + mi * 16 + orow;
      size_t c  = colB0 + wn * 64 + ni * 16 + ocol;
      #pragma unroll
      for (int j = 0; j < 4; ++j)
        Cp[(r0 + j) * (size_t)N + c] = acc[mi][ni][j];
    }
  }
}

// ---------- KQ reduce: sum 8 partials [128][4096], split hi/lo -> KQ2 [256][4096] bf16 ----------

__global__ void kq_reduce(const float* __restrict__ KQpart, unsigned short* __restrict__ KQ2) {
  int idx = blockIdx.x * blockDim.x + threadIdx.x;   // over 128*4096, idx = l*4096 + j
  if (idx >= 128 * 4096) return;
  float s = 0.f;
  #pragma unroll
  for (int ks = 0; ks < 8; ++ks) s += KQpart[(size_t)ks * 128 * 4096 + idx];
  unsigned short hi = bf16r(s);
  unsigned short lo = bf16r(s - bf16f(hi));
  int l = idx >> 12, j = idx & 4095;
  KQ2[(size_t)l * 4096 + j]         = hi;
  KQ2[(size_t)(l + 128) * 4096 + j] = lo;
}

// ---------- softmax: sum 4 ks-partials + hi/lo col fold + bias -> duplicated [W|W] bf16 [rows][256] ----------

__global__ void softmax_fused2(const float* __restrict__ Spart, const float* __restrict__ sbias,
                               unsigned short* __restrict__ W2, int rows) {
  int wave = threadIdx.x >> 6;
  int lane = threadIdx.x & 63;
  int row = blockIdx.x * (blockDim.x >> 6) + wave;
  if (row >= rows) return;
  const float scale = 0.088388347648318447f;   // 1/sqrt(128)
  float sx = 0.f, sy = 0.f;
  #pragma unroll
  for (int ks = 0; ks < 4; ++ks) {
    const float* P = Spart + ((size_t)ks * rows + row) * 256;
    float2 a = reinterpret_cast<const float2*>(P)[lane];          // hi cols
    float2 b = reinterpret_cast<const float2*>(P + 128)[lane];    // lo cols
    sx += a.x + b.x; sy += a.y + b.y;
  }
  float2 bb = reinterpret_cast<const float2*>(sbias)[lane];
  sx += bb.x; sy += bb.y;
  int c0 = lane * 2, c1 = c0 + 1;
  float s0 = (c0 <= 100) ? sx * scale : -1e30f;
  float s1 = (c1 <= 100) ? sy * scale : -1e30f;
  float m = fmaxf(s0, s1);
  #pragma unroll
  for (int off = 1; off < 64; off <<= 1) m = fmaxf(m, __shfl_xor(m, off));
  float e0 = (c0 <= 100) ? __expf(s0 - m) : 0.f;
  float e1 = (c1 <= 100) ? __expf(s1 - m) : 0.f;
  float sum = e0 + e1;
  #pragma unroll
  for (int off = 1; off < 64; off <<= 1) sum += __shfl_xor(sum, off);
  float inv = 1.f / sum;
  ushort2 o;
  o.x = bf16r(e0 * inv);
  o.y = bf16r(e1 * inv);
  reinterpret_cast<ushort2*>(W2 + (size_t)row * 256)[lane] = o;
  reinterpret_cast<ushort2*>(W2 + (size_t)row * 256 + 128)[lane] = o;
}

// ---------- VO reduce: sum 8 partials [4096][128], split hi/lo -> VOT2 [4096][256] bf16 ----------

__global__ void vo_reduce(const float* __restrict__ VOpart, unsigned short* __restrict__ VOT2) {
  int idx = blockIdx.x * blockDim.x + threadIdx.x;   // over 4096*128, idx = o*128 + l
  if (idx >= 4096 * 128) return;
  float s = 0.f;
  #pragma unroll
  for (int ks = 0; ks < 8; ++ks) s += VOpart[(size_t)ks * 4096 * 128 + idx];
  unsigned short hi = bf16r(s);
  unsigned short lo = bf16r(s - bf16f(hi));
  int o = idx >> 7, l = idx & 127;
  VOT2[(size_t)o * 256 + l]       = hi;
  VOT2[(size_t)o * 256 + 128 + l] = lo;
}

// ---------- m97-style 128^2 NT GEMM (final: out = W2 @ VOT2^T + out_b) ----------

template<bool ADD_BIAS, bool OUT_F32>
__global__ void gemm_nt(const unsigned short* __restrict__ A,
                        const unsigned short* __restrict__ B,
                        const float* __restrict__ bias,
                        void* __restrict__ Cout,
                        int M, int N, int K) {
  __shared__ unsigned short As[128][32];
  __shared__ unsigned short Bs[128][32];

  const int tid  = threadIdx.x;
  const int wave = tid >> 6;
  const int lane = tid & 63;
  const int wm = wave >> 1;
  const int wn = wave & 1;
  const size_t rowA0 = (size_t)blockIdx.y * 128;
  const size_t colB0 = (size_t)blockIdx.x * 128;

  f32x4 acc[4][4] = {};

  const int sr = wave * 16 + (lane >> 2);
  const int sc = (lane & 3) << 3;

  const unsigned short* Ap0 = A + (rowA0 + sr) * (size_t)K + sc;
  const unsigned short* Ap1 = A + (rowA0 + 64 + sr) * (size_t)K + sc;
  const unsigned short* Bp0 = B + (colB0 + sr) * (size_t)K + sc;
  const unsigned short* Bp1 = B + (colB0 + 64 + sr) * (size_t)K + sc;
  unsigned short* AsD0 = &As[wave * 16][0];
  unsigned short* AsD1 = &As[64 + wave * 16][0];
  unsigned short* BsD0 = &Bs[wave * 16][0];
  unsigned short* BsD1 = &Bs[64 + wave * 16][0];

  const int fr = lane & 15;
  const int fk = (lane >> 4) << 3;

  for (int k0 = 0; k0 < K; k0 += 32) {
    gload_lds16(Ap0 + k0, AsD0);
    gload_lds16(Ap1 + k0, AsD1);
    gload_lds16(Bp0 + k0, BsD0);
    gload_lds16(Bp1 + k0, BsD1);
    __syncthreads();

    short8 av[4], bv[4];
    #pragma unroll
    for (int mi = 0; mi < 4; ++mi)
      av[mi] = *reinterpret_cast<const short8*>(&As[wm * 64 + mi * 16 + fr][fk]);
    #pragma unroll
    for (int ni = 0; ni < 4; ++ni)
      bv[ni] = *reinterpret_cast<const short8*>(&Bs[wn * 64 + ni * 16 + fr][fk]);
    #pragma unroll
    for (int mi = 0; mi < 4; ++mi)
      #pragma unroll
      for (int ni = 0; ni < 4; ++ni)
        acc[mi][ni] = __builtin_amdgcn_mfma_f32_16x16x32_bf16(av[mi], bv[ni], acc[mi][ni], 0, 0, 0);
    __syncthreads();
  }

  const int orow = (lane >> 4) * 4;
  const int ocol = lane & 15;
  #pragma unroll
  for (int mi = 0; mi < 4; ++mi) {
    #pragma unroll
    for (int ni = 0; ni < 4; ++ni) {
      size_t r0 = rowA0 + wm * 64 + mi * 16 + orow;
      size_t c  = colB0 + wn * 64 + ni * 16 + ocol;
      float bv_ = ADD_BIAS ? bias[c] : 0.f;
      #pragma unroll
      for (int j = 0; j < 4; ++j) {
        float v = acc[mi][ni][j] + bv_;
        if (OUT_F32) ((float*)Cout)[(r0 + j) * (size_t)N + c] = v;
        else         ((unsigned short*)Cout)[(r0 + j) * (size_t)N + c] = bf16r(v);
      }
    }
  }
}

// ---------- launch ----------

extern "C" void kernel_launch(void* const* d_in, const int* in_sizes, int n_in,
                              void* d_out, int out_size, void* d_ws, size_t ws_size,
                              hipStream_t stream) {
  const float* x       = (const float*)d_in[0];   // [8192,4096]
  const float* q_w     = (const float*)d_in[1];   // [4096,4096]
  const float* q_b     = (const float*)d_in[2];   // [4096]
  const float* k_cache = (const float*)d_in[3];   // [100,4096]
  const float* v_cache = (const float*)d_in[4];   // [100,4096]
  const float* out_w   = (const float*)d_in[5];   // [4096,4096]
  const float* out_b   = (const float*)d_in[6];   // [4096]
  float* out = (float*)d_out;

  const int M = 8192, H = 4096;

  char* ws = (char*)d_ws;
  size_t off = 0;
  auto alloc = [&](size_t bytes) { void* p = ws + off; off += (bytes + 255) & ~(size_t)255; return p; };
  unsigned short* qwt2   = (unsigned short*)alloc((size_t)H * 8192 * 2);   // 67 MB  q_w^T hi|lo
  unsigned short* kpad2  = (unsigned short*)alloc((size_t)128 * 8192 * 2); // 2 MB   [kpad|kpad]
  unsigned short* vpad   = (unsigned short*)alloc((size_t)128 * H * 2);    // 1 MB
  float*          sbias  = (float*)alloc(128 * 4);
  unsigned short* KQ2    = (unsigned short*)alloc((size_t)256 * H * 2);    // 2 MB   [KQ_hi;KQ_lo]
  unsigned short* W2     = (unsigned short*)alloc((size_t)M * 256 * 2);    // 4 MB   [W|W]
  unsigned short* VOT2   = (unsigned short*)alloc((size_t)H * 256 * 2);    // 2 MB   [VO^T hi|lo]
  float*          scratch= (float*)alloc((size_t)32 << 20);                // 32 MB  KQpart/Spart/VOTpart
  if (ws_size < off) { fprintf(stderr, "ws too small: need %zu have %zu\n", off, ws_size); return; }

  // 1) weight/cache preprocessing (all small or read-once)
  transpose_hilo<<<dim3(64, 64), 256, 0, stream>>>(q_w, qwt2);
  build_pad_dup<<<2048, 256, 0, stream>>>(k_cache, kpad2);
  build_pad128<<<2048, 256, 0, stream>>>(v_cache, vpad);
  kq_bias<<<128, 64, 0, stream>>>(k_cache, q_b, sbias);

  // 2) KQ = kpad @ q_w  (via [kpad|kpad] @ [qwt_hi|qwt_lo]^T, K=8192), split-K 8
  gemm_ntk_splitk<<<dim3(8, 1, 32), 256, 0, stream>>>(kpad2, qwt2, scratch, 128, H, 8192, 1024);
  kq_reduce<<<2048, 256, 0, stream>>>(scratch, KQ2);

  // 3) S = x @ KQ2^T (N=256: hi/lo planes), split-K 4, x read f32 + in-reg cvt
  gemm_ntf_splitk<<<dim3(8, 64, 1), 256, 0, stream>>>(x, KQ2, scratch, M, 256, H, 1024, 1);

  // 4) softmax (ks-sum + hi/lo fold + bias) -> W2 [8192][256] dup
  softmax_fused2<<<M / 4, 256, 0, stream>>>(scratch, sbias, W2, M);

  // 5) VO^T = out_w @ vpad^T (out_w read f32 + in-reg cvt), split-K 8
  gemm_ntf_splitk<<<dim3(8, 32, 1), 256, 0, stream>>>(out_w, vpad, scratch, H, 128, H, 512, 0);
  vo_reduce<<<2048, 256, 0, stream>>>(scratch, VOT2);

  // 6) out = W2 @ VOT2^T + out_b  (K=256: [W|W] x [hi|lo])
  gemm_nt<true, true><<<dim3(H / 128, M / 128), 256, 0, stream>>>(W2, VOT2, out_b, out, M, H, 256);
}